// Round 7
// baseline (156.707 us; speedup 1.0000x reference)
//
#include <hip/hip_runtime.h>
#include <hip/hip_bf16.h>
#include <math.h>

#define BATCH 4096
#define INDIM 512
#define NDIM  1024
#define NG    16

typedef __bf16 bf16_t;
typedef __bf16 bf16x8 __attribute__((ext_vector_type(8)));
typedef float  f32x4  __attribute__((ext_vector_type(4)));
typedef unsigned int u32;
typedef unsigned int u32x4 __attribute__((ext_vector_type(4)));

__device__ __forceinline__ float gelu_exact(float v) {
    return 0.5f * v * (1.0f + erff(v * 0.70710678118654752440f));
}

__device__ __forceinline__ void gload_lds16(const void* g, void* l) {
    __builtin_amdgcn_global_load_lds((const __attribute__((address_space(1))) void*)g,
                                     (__attribute__((address_space(3))) void*)l,
                                     16, 0, 0);
}

// ---------------- deterministic per-genre bucketing ----------------
__global__ __launch_bounds__(256)
void build_perm_kernel(const int* __restrict__ genre,
                       int* __restrict__ perm,
                       int* __restrict__ offsets /* NG+1 ints */) {
    __shared__ int cc[64][NG];
    __shared__ int gtot[NG];
    __shared__ int goff[NG];
    const int t = threadIdx.x;
    for (int i = t; i < 64 * NG; i += 256) (&cc[0][0])[i] = 0;
    __syncthreads();
    if (t < 64) {
        #pragma unroll 1
        for (int i = 0; i < 64; ++i) {
            int g = genre[t * 64 + i] & (NG - 1);
            cc[t][g] += 1;
        }
    }
    __syncthreads();
    if (t < NG) {
        int s = 0;
        #pragma unroll 1
        for (int c = 0; c < 64; ++c) { int v = cc[c][t]; cc[c][t] = s; s += v; }
        gtot[t] = s;
    }
    __syncthreads();
    if (t == 0) {
        int s = 0;
        for (int g = 0; g < NG; ++g) { goff[g] = s; offsets[g] = s; s += gtot[g]; }
        offsets[NG] = s;
    }
    __syncthreads();
    if (t < 64) {
        #pragma unroll 1
        for (int i = 0; i < 64; ++i) {
            int b = t * 64 + i;
            int g = genre[b] & (NG - 1);
            int pos = goff[g] + cc[t][g];
            cc[t][g] += 1;
            perm[pos] = b;
        }
    }
}

// ---------------- x: fp32 -> bf16 ----------------
__global__ __launch_bounds__(256)
void convert_x_kernel(const float* __restrict__ src, bf16_t* __restrict__ dst) {
    const int i = (blockIdx.x * 256 + threadIdx.x) * 8;  // grid sized exactly
    float4 a = *(const float4*)&src[i];
    float4 b = *(const float4*)&src[i + 4];
    bf16x8 w;
    w[0] = (bf16_t)a.x; w[1] = (bf16_t)a.y; w[2] = (bf16_t)a.z; w[3] = (bf16_t)a.w;
    w[4] = (bf16_t)b.x; w[5] = (bf16_t)b.y; w[6] = (bf16_t)b.z; w[7] = (bf16_t)b.w;
    *(bf16x8*)&dst[i] = w;
}

// ---------------- weight transpose+convert: fp32 [K][N] -> bf16 [N][K] ----------------
__device__ __forceinline__ u32 pkbf(float a, float b) {
    union { bf16_t h[2]; u32 v; } x;
    x.h[0] = (bf16_t)a; x.h[1] = (bf16_t)b;
    return x.v;
}

__device__ __forceinline__ void transpose_tile(const float* __restrict__ src,
                                               bf16_t* __restrict__ dst,
                                               int K, int N, int k0, int n0, int t) {
    __shared__ u32 T[64][17];  // [n][kpair], pad 17 -> bank-spread
    {
        const int kr = (t >> 4) * 2;       // 0..30
        const int nc = (t & 15) * 4;       // 0..60
        const float* p0 = src + (size_t)(k0 + kr) * N + n0 + nc;
        const float* p1 = p0 + N;
        float4 r0 = *(const float4*)p0;
        float4 r1 = *(const float4*)p1;
        const int kp = t >> 4;
        T[nc + 0][kp] = pkbf(r0.x, r1.x);
        T[nc + 1][kp] = pkbf(r0.y, r1.y);
        T[nc + 2][kp] = pkbf(r0.z, r1.z);
        T[nc + 3][kp] = pkbf(r0.w, r1.w);
    }
    __syncthreads();
    {
        const int n = t >> 2;          // 0..63
        const int c = t & 3;           // 16B chunk of the 64B row
        u32x4 v;
        v.x = T[n][c * 4 + 0];
        v.y = T[n][c * 4 + 1];
        v.z = T[n][c * 4 + 2];
        v.w = T[n][c * 4 + 3];
        *(u32x4*)((char*)dst + ((size_t)(n0 + n) * K + k0 + c * 8) * 2) = v;
    }
}

__global__ __launch_bounds__(256)
void transpose_w_kernel(const float* __restrict__ src, bf16_t* __restrict__ dst,
                        int K, int N) {
    const size_t slab = (size_t)blockIdx.z * (size_t)K * (size_t)N;
    transpose_tile(src + slab, dst + slab, K, N, blockIdx.x * 32, blockIdx.y * 64,
                   threadIdx.x);
}

// Wa and Wb in one launch: z in [0,32), z<16 -> Wa slab z, else Wb slab z-16.
__global__ __launch_bounds__(256)
void transpose_w2_kernel(const float* __restrict__ srcA, bf16_t* __restrict__ dstA,
                         const float* __restrict__ srcB, bf16_t* __restrict__ dstB) {
    const int z = blockIdx.z;
    const size_t slab = (size_t)(z & 15) * NDIM * NDIM;
    const float* s = (z < 16 ? srcA : srcB) + slab;
    bf16_t*      d = (z < 16 ? dstA : dstB) + slab;
    transpose_tile(s, d, NDIM, NDIM, blockIdx.x * 32, blockIdx.y * 64, threadIdx.x);
}

// ---- 64x128 MFMA GEMM, 512 threads (8 waves 2x4), 2-phase + T2 XOR swizzle ----
// A: bf16 [M][K] (optionally row-gathered via perm). Bt: bf16 [N][K] (or [G][N][K]).
// BM=64 BN=128 BK=64; wave tile 32x32 (2x2 frags). LDS 48 KB double-buffered ->
// 3 blocks/CU capacity; grids 512-640 blocks = 2-2.5 blocks/CU of cross-block TLP
// (the lever r5/r6 showed: intra-block TLP can't fill the lockstep barrier time).
// Sync structure unchanged: counted vmcnt (3 loads/stage), raw s_barrier,
// both-sides XOR swizzle (LDS dest linear, global-source chunk ^= row&7).
template<bool EXPERT, bool GATHER_A, bool GELU_OUT, bool SCATTER_OUT, bool OUT_BF16>
__global__ __launch_bounds__(512, 6)
void gemm64_kernel(const bf16_t* __restrict__ A,
                   const bf16_t* __restrict__ Bt,
                   const float* __restrict__ bias,
                   void* __restrict__ Cout,
                   int K,
                   const int* __restrict__ perm,
                   const int* __restrict__ offsets) {
    constexpr int N = NDIM;
    __shared__ bf16_t As[2][64 * 64];    // [row][k], row stride 128B, linear dest
    __shared__ bf16_t Bs[2][128 * 64];   // [n][k]

    const int n0 = blockIdx.y * 128;
    int m0 = 0, mloc0 = 0, count = 1 << 30, gbase = 0;
    const bf16_t* Bp = Bt;
    const float* biasp = bias;

    if constexpr (EXPERT) {
        const int bx = blockIdx.x;
        int g = 0, accum = 0, cnt = 0;
        for (; g < NG; ++g) {
            cnt = offsets[g + 1] - offsets[g];
            int nt = (cnt + 63) >> 6;
            if (bx < accum + nt) break;
            accum += nt;
        }
        if (g >= NG) return;  // beyond real tile total (whole block exits pre-barrier)
        count = cnt;
        mloc0 = (bx - accum) * 64;
        gbase = offsets[g];
        m0 = gbase + mloc0;
        Bp = Bt + (size_t)g * N * NDIM;
        biasp = bias + g * N;
    } else {
        m0 = blockIdx.x * 64;
    }

    const int tid  = threadIdx.x;
    const int wave = tid >> 6;
    const int lane = tid & 63;
    const int l15  = lane & 15;
    const int l16  = lane >> 4;
    const int wr   = wave >> 2;   // 0..1 -> 32-row band
    const int wc   = wave & 3;    // 0..3 -> 32-col band

    // staging: thread t covers LDS row (t>>3) (A; B rows +0 and +64), in-row 16B
    // chunk (t&7). Swizzled global chunk = (t&7) ^ (row&7) = (t&7) ^ ((t>>3)&7).
    const int srow   = tid >> 3;                              // 0..63
    const int srcoff = (((tid & 7) ^ ((tid >> 3) & 7)) * 16);
    int arow;
    if constexpr (EXPERT) {
        int rcl = mloc0 + srow;
        if (rcl >= count) rcl = count - 1;   // clamp tail inside genre
        arow = GATHER_A ? perm[gbase + rcl] : (gbase + rcl);
    } else {
        arow = m0 + srow;
    }
    const char* aptr  = (const char*)(A + (size_t)arow * K) + srcoff;
    const char* bptr0 = (const char*)(Bp + (size_t)(n0 + srow) * K) + srcoff;
    const char* bptr1 = (const char*)(Bp + (size_t)(n0 + 64 + srow) * K) + srcoff;

    f32x4 acc[2][2];
    #pragma unroll
    for (int m = 0; m < 2; ++m)
        #pragma unroll
        for (int n = 0; n < 2; ++n)
            acc[m][n] = (f32x4){0.f, 0.f, 0.f, 0.f};

    const int nsteps = K >> 6;
    const int t16 = tid * 16;

    // 3 x global_load_lds(16B) per thread per stage (1 A + 2 B)
    auto stage = [&](int buf, int t) {
        const size_t ko = (size_t)t * 128;  // 64 bf16 = 128 bytes along K
        gload_lds16(aptr  + ko, (char*)&As[buf][0] + t16);
        gload_lds16(bptr0 + ko, (char*)&Bs[buf][0] + t16);
        gload_lds16(bptr1 + ko, (char*)&Bs[buf][0] + 8192 + t16);
    };

    stage(0, 0);
    int cur = 0;
    for (int t = 0; t < nsteps; ++t) {
        if (t + 1 < nsteps) {
            stage(cur ^ 1, t + 1);
            // wait only for STAGE(t)'s 3 loads; STAGE(t+1)'s 3 stay in flight
            asm volatile("s_waitcnt vmcnt(3)" ::: "memory");
        } else {
            asm volatile("s_waitcnt vmcnt(0)" ::: "memory");
        }
        asm volatile("s_barrier" ::: "memory");

        #pragma unroll
        for (int kk = 0; kk < 2; ++kk) {
            bf16x8 a[2], b[2];
            #pragma unroll
            for (int m = 0; m < 2; ++m) {
                const int row = wr * 32 + m * 16 + l15;
                const int chunk = (kk * 4 + l16) ^ (lane & 7);  // swizzled read
                a[m] = *(const bf16x8*)&As[cur][row * 64 + chunk * 8];
            }
            #pragma unroll
            for (int n = 0; n < 2; ++n) {
                const int row = wc * 32 + n * 16 + l15;
                const int chunk = (kk * 4 + l16) ^ (lane & 7);
                b[n] = *(const bf16x8*)&Bs[cur][row * 64 + chunk * 8];
            }
            #pragma unroll
            for (int m = 0; m < 2; ++m)
                #pragma unroll
                for (int n = 0; n < 2; ++n)
                    acc[m][n] = __builtin_amdgcn_mfma_f32_16x16x32_bf16(a[m], b[n], acc[m][n], 0, 0, 0);
        }
        asm volatile("s_barrier" ::: "memory");  // reads done before buf[cur] is re-staged
        cur ^= 1;
    }

    // ---- epilogue: bias (+GELU), masked/scattered store
    #pragma unroll
    for (int n = 0; n < 2; ++n) {
        const int col = n0 + wc * 32 + n * 16 + l15;
        const float bv = biasp[col];
        #pragma unroll
        for (int m = 0; m < 2; ++m) {
            #pragma unroll
            for (int r = 0; r < 4; ++r) {
                const int row_local = wr * 32 + m * 16 + l16 * 4 + r;
                if constexpr (EXPERT) {
                    if (mloc0 + row_local >= count) continue;
                }
                float v = acc[m][n][r] + bv;
                if constexpr (GELU_OUT) v = gelu_exact(v);
                int orow = m0 + row_local;
                if constexpr (SCATTER_OUT) orow = perm[orow];
                if constexpr (OUT_BF16)
                    ((bf16_t*)Cout)[(size_t)orow * N + col] = (bf16_t)v;
                else
                    ((float*)Cout)[(size_t)orow * N + col] = v;
            }
        }
    }
}

extern "C" void kernel_launch(void* const* d_in, const int* in_sizes, int n_in,
                              void* d_out, int out_size, void* d_ws, size_t ws_size,
                              hipStream_t stream) {
    const float* x     = (const float*)d_in[0];
    const int*   genre = (const int*)  d_in[1];
    const float* W1    = (const float*)d_in[2];
    const float* b1    = (const float*)d_in[3];
    const float* W2    = (const float*)d_in[4];
    const float* b2    = (const float*)d_in[5];
    const float* Wa    = (const float*)d_in[6];
    const float* ba    = (const float*)d_in[7];
    const float* Wb    = (const float*)d_in[8];
    const float* bb    = (const float*)d_in[9];
    float* out = (float*)d_out;

    char* ws = (char*)d_ws;
    const size_t MB = 1 << 20;
    bf16_t* W1t = (bf16_t*)(ws);                 // 1 MB  [1024][512]
    bf16_t* W2t = (bf16_t*)(ws + 1 * MB);        // 2 MB  [1024][1024]
    bf16_t* Wat = (bf16_t*)(ws + 3 * MB);        // 32 MB [16][1024][1024]
    bf16_t* Wbt = (bf16_t*)(ws + 35 * MB);       // 32 MB
    bf16_t* xb  = (bf16_t*)(ws + 67 * MB);       // 4 MB  [4096][512]
    bf16_t* s1b = (bf16_t*)(ws + 71 * MB);       // 8 MB  [4096][1024] (reused as h)
    bf16_t* sb  = (bf16_t*)(ws + 79 * MB);       // 8 MB
    int*    perm    = (int*)(ws + 87 * MB);      // 16 KB
    int*    offsets = (int*)(ws + 87 * MB + 65536);
    bf16_t* hb = s1b;  // s1 dead after GEMM2

    build_perm_kernel<<<1, 256, 0, stream>>>(genre, perm, offsets);
    convert_x_kernel<<<BATCH * INDIM / (256 * 8), 256, 0, stream>>>(x, xb);
    transpose_w_kernel<<<dim3(INDIM / 32, NDIM / 64, 1), 256, 0, stream>>>(W1, W1t, INDIM, NDIM);
    transpose_w_kernel<<<dim3(NDIM / 32, NDIM / 64, 1),  256, 0, stream>>>(W2, W2t, NDIM, NDIM);
    transpose_w2_kernel<<<dim3(NDIM / 32, NDIM / 64, 2 * NG), 256, 0, stream>>>(
        Wa, Wat, Wb, Wbt);

    // trunk: s1 = gelu(x @ W1 + b1)
    gemm64_kernel<false, false, true, false, true><<<dim3(64, 8), 512, 0, stream>>>(
        xb, W1t, b1, s1b, INDIM, nullptr, nullptr);
    // trunk: s = gelu(s1 @ W2 + b2)
    gemm64_kernel<false, false, true, false, true><<<dim3(64, 8), 512, 0, stream>>>(
        s1b, W2t, b2, sb, NDIM, nullptr, nullptr);
    // experts: h[perm-space] = gelu(s[perm] @ Wa[g] + ba[g])
    gemm64_kernel<true, true, true, false, true><<<dim3(80, 8), 512, 0, stream>>>(
        sb, Wat, ba, hb, NDIM, perm, offsets);
    // experts: out[perm] = h @ Wb[g] + bb[g]
    gemm64_kernel<true, false, false, true, false><<<dim3(80, 8), 512, 0, stream>>>(
        hb, Wbt, bb, out, NDIM, perm, offsets);
}